// Round 1
// baseline (1260.939 us; speedup 1.0000x reference)
//
#include <hip/hip_runtime.h>

// Problem constants
#define DIMV   64
#define NEMB   1024
#define NROWS  262144          // B*T = 2048*128
#define DECAYF 0.99f
#define OMDF   0.01f           // 1 - decay
#define EPSF   1e-5f

// d_out layout (floats): quantize | loss | new_embed | new_cluster_size | new_embed_avg
#define OQ   0
#define OL   16777216
#define OE   16777217
#define ONC  16842753
#define OA   16843777

// d_ws layout (floats)
#define WS_E2    0        // 1024: ||e_k||^2
#define WS_CNT   1024     // 1024: counts
#define WS_ESUM  2048     // 65536: embed_sum [d][k]
#define WS_LOSS  67584    // 1: loss accumulator
#define WS_TOTAL 67585    // 1: sum(new_cluster_size)

// ---------------------------------------------------------------- e2 precompute
__global__ void vq_e2(const float* __restrict__ embed, float* __restrict__ e2)
{
    int k = blockIdx.x * 256 + threadIdx.x;   // k < 1024
    float s = 0.f;
    #pragma unroll
    for (int d = 0; d < DIMV; d++) {
        float v = embed[d * NEMB + k];
        s = fmaf(v, v, s);
    }
    e2[k] = s;
}

// ---------------------------------------------------------------- main: argmin + gather + loss + EMA scatter
__global__ __launch_bounds__(256, 4) void vq_main(
    const float* __restrict__ x, const int* __restrict__ mask,
    const float* __restrict__ embed, const float* __restrict__ e2g,
    float* __restrict__ out, float* __restrict__ counts,
    float* __restrict__ esum, float* __restrict__ lossacc)
{
    __shared__ float etile[128][68];   // [kk][d], pad 64->68 to break store bank conflicts
    __shared__ float e2s[128];

    const int tid = threadIdx.x;
    const int row = blockIdx.x * 256 + tid;

    // x row -> registers (16 x float4 = 64 VGPRs)
    float4 xv[16];
    {
        const float4* xp = (const float4*)(x + (size_t)row * DIMV);
        #pragma unroll
        for (int i = 0; i < 16; i++) xv[i] = xp[i];
    }
    float x2 = 0.f;
    #pragma unroll
    for (int i = 0; i < 16; i++)
        x2 += xv[i].x * xv[i].x + xv[i].y * xv[i].y + xv[i].z * xv[i].z + xv[i].w * xv[i].w;

    float best = 3.4e38f;
    int   bestk = 0;

    for (int kt = 0; kt < NEMB; kt += 128) {
        __syncthreads();
        // cooperative load of 64x128 tile, transposed into LDS
        #pragma unroll
        for (int i = 0; i < 32; i++) {
            int lin = i * 256 + tid;
            int d   = lin >> 7;      // 0..63
            int kk  = lin & 127;     // 0..127  (consecutive tid -> coalesced global read)
            etile[kk][d] = embed[d * NEMB + kt + kk];
        }
        if (tid < 128) e2s[tid] = e2g[kt + tid];
        __syncthreads();

        for (int kk = 0; kk < 128; kk++) {
            const float4* ep = (const float4*)(&etile[kk][0]);  // row base 272B: 16B aligned
            float ax = 0.f, ay = 0.f, az = 0.f, aw = 0.f;       // 4 chains for ILP
            #pragma unroll
            for (int i = 0; i < 16; i++) {
                float4 ev = ep[i];   // wave-uniform address -> LDS broadcast (free)
                ax = fmaf(xv[i].x, ev.x, ax);
                ay = fmaf(xv[i].y, ev.y, ay);
                az = fmaf(xv[i].z, ev.z, az);
                aw = fmaf(xv[i].w, ev.w, aw);
            }
            float dot  = (ax + ay) + (az + aw);
            float dist = (x2 - 2.0f * dot) + e2s[kk];  // same shape as np formula
            if (dist < best) { best = dist; bestk = kt + kk; }  // strict < : first index wins
        }
    }

    // ---- epilogue: gather code, straight-through write, loss, EMA scatter ----
    const bool valid = (mask[row] == 0);   // valid = ~mask
    float sq = 0.f;
    float4* qp = (float4*)(out + OQ + (size_t)row * DIMV);
    #pragma unroll
    for (int i = 0; i < 16; i++) {
        float4 xvv = xv[i];
        float e0 = embed[(4 * i + 0) * NEMB + bestk];
        float e1 = embed[(4 * i + 1) * NEMB + bestk];
        float e2v = embed[(4 * i + 2) * NEMB + bestk];
        float e3 = embed[(4 * i + 3) * NEMB + bestk];
        // replicate straight-through rounding: q = x + (e - x)
        float q0 = xvv.x + (e0 - xvv.x);
        float q1 = xvv.y + (e1 - xvv.y);
        float q2 = xvv.z + (e2v - xvv.z);
        float q3 = xvv.w + (e3 - xvv.w);
        float4 q4 = {q0, q1, q2, q3};
        qp[i] = q4;
        float d0 = q0 - xvv.x, d1 = q1 - xvv.y, d2 = q2 - xvv.z, d3 = q3 - xvv.w;
        sq += d0 * d0 + d1 * d1 + d2 * d2 + d3 * d3;
        if (valid) {
            atomicAdd(&esum[(4 * i + 0) * NEMB + bestk], xvv.x);
            atomicAdd(&esum[(4 * i + 1) * NEMB + bestk], xvv.y);
            atomicAdd(&esum[(4 * i + 2) * NEMB + bestk], xvv.z);
            atomicAdd(&esum[(4 * i + 3) * NEMB + bestk], xvv.w);
        }
    }
    if (valid) atomicAdd(&counts[bestk], 1.0f);

    // loss: wave-reduce then one atomic per wave
    float v = valid ? sq : 0.0f;
    #pragma unroll
    for (int off = 32; off > 0; off >>= 1) v += __shfl_down(v, off, 64);
    if ((tid & 63) == 0) atomicAdd(lossacc, v);
}

// ---------------------------------------------------------------- finalize A: cluster size, total, loss
__global__ __launch_bounds__(1024) void vq_finalA(
    const float* __restrict__ cluster_size, const float* __restrict__ counts,
    const float* __restrict__ lossacc, float* __restrict__ out,
    float* __restrict__ total_ws)
{
    __shared__ float s1[1024];  // sum of new_cluster_size
    __shared__ float s2[1024];  // sum of counts (= n_valid)
    int k = threadIdx.x;
    float c   = counts[k];
    float ncs = cluster_size[k] * DECAYF + OMDF * c;
    out[ONC + k] = ncs;
    s1[k] = ncs; s2[k] = c;
    __syncthreads();
    for (int off = 512; off > 0; off >>= 1) {
        if (k < off) { s1[k] += s1[k + off]; s2[k] += s2[k + off]; }
        __syncthreads();
    }
    if (k == 0) {
        total_ws[0] = s1[0];
        out[OL] = lossacc[0] / (s2[0] * (float)DIMV);
    }
}

// ---------------------------------------------------------------- finalize B: embed_avg, embed
__global__ void vq_finalB(const float* __restrict__ embed_avg,
                          const float* __restrict__ esum,
                          float* __restrict__ out,
                          const float* __restrict__ total_ws)
{
    int idx = blockIdx.x * 256 + threadIdx.x;  // < 65536, idx = d*1024 + k
    int k = idx & (NEMB - 1);
    float avg = embed_avg[idx] * DECAYF + OMDF * esum[idx];
    out[OA + idx] = avg;
    float ncs   = out[ONC + k];
    float total = *total_ws;
    float sm = (ncs + EPSF) / (total + (float)NEMB * EPSF) * total;
    out[OE + idx] = avg / sm;
}

// ---------------------------------------------------------------- launcher
extern "C" void kernel_launch(void* const* d_in, const int* in_sizes, int n_in,
                              void* d_out, int out_size, void* d_ws, size_t ws_size,
                              hipStream_t stream)
{
    const float* x            = (const float*)d_in[0];
    const int*   mask         = (const int*)d_in[1];
    const float* embed        = (const float*)d_in[2];
    const float* cluster_size = (const float*)d_in[3];
    const float* embed_avg    = (const float*)d_in[4];
    float* out = (float*)d_out;
    float* ws  = (float*)d_ws;

    // zero accumulators (counts, esum, loss, total) + e2 region
    hipMemsetAsync(ws, 0, (size_t)67600 * sizeof(float), stream);

    vq_e2<<<NEMB / 256, 256, 0, stream>>>(embed, ws + WS_E2);
    vq_main<<<NROWS / 256, 256, 0, stream>>>(x, mask, embed, ws + WS_E2, out,
                                             ws + WS_CNT, ws + WS_ESUM, ws + WS_LOSS);
    vq_finalA<<<1, 1024, 0, stream>>>(cluster_size, ws + WS_CNT, ws + WS_LOSS,
                                      out, ws + WS_TOTAL);
    vq_finalB<<<65536 / 256, 256, 0, stream>>>(embed_avg, ws + WS_ESUM, out, ws + WS_TOTAL);
}